// Round 1
// 628.926 us; speedup vs baseline: 1.0707x; 1.0707x over previous
//
#include <hip/hip_runtime.h>
#include <math.h>

#define BATCH 256
#define ISZ 256
#define H 512
#define BH (BATCH * H)       // 131072
#define CLIPV 2.0f

typedef float f4_t __attribute__((ext_vector_type(4)));

__device__ __forceinline__ float sigmoidf_(float x) { return 1.0f / (1.0f + expf(-x)); }
__device__ __forceinline__ f4_t nt_load4(const f4_t* p) { return __builtin_nontemporal_load(p); }
__device__ __forceinline__ void nt_store4(f4_t* p, f4_t v) { __builtin_nontemporal_store(v, p); }

// ---------------- K-A: merged small GEMMs + einsum partials ----------------
// blocks [0, 160):   z = bid>>5 GEMM tiles (same math as previous small_gemms)
// blocks [160, 2208): einsum partial hbpart[b,hseg,k] = sum_{h in 64-seg} h0*hebb
//   (compute-bound GEMMs overlap the HBM-bound hebb stream in one launch;
//    this read also primes L3 with the tail of hebb for the reversed update)
#define BT 64
#define KT 32
#define LDSP (BT + 4)
#define NGEMM 160
#define NEIN  2048

__global__ __launch_bounds__(256) void gemms_einsum(
    const float* __restrict__ x, const float* __restrict__ h0,
    const float* __restrict__ x2f_w, const float* __restrict__ x2f_b,
    const float* __restrict__ h2f_w, const float* __restrict__ h2f_b,
    const float* __restrict__ x2i_w, const float* __restrict__ x2i_b,
    const float* __restrict__ h2i_w, const float* __restrict__ h2i_b,
    const float* __restrict__ x2o_w, const float* __restrict__ x2o_b,
    const float* __restrict__ h2o_w, const float* __restrict__ h2o_b,
    const float* __restrict__ x2c_w, const float* __restrict__ x2c_b,
    const float* __restrict__ w,
    const float* __restrict__ hebb,
    float* __restrict__ pre, float* __restrict__ hbpart)
{
  __shared__ __align__(16) float As[KT][LDSP];
  __shared__ __align__(16) float Bs[KT][LDSP];
  __shared__ float h0s[64];
  __shared__ f4_t redv[128];

  const int bid = blockIdx.x;
  const int t   = threadIdx.x;

  if (bid >= NGEMM) {
    // ---- einsum path: (b, hseg) over 64 h-rows, 256 threads (2 half-rows x 128 cols4)
    const int e    = bid - NGEMM;
    const int b    = e >> 3;
    const int hseg = e & 7;
    const int col  = t & 127;
    const int half = t >> 7;
    if (t < 64) h0s[t] = h0[b * H + hseg * 64 + t];
    __syncthreads();
    const f4_t* hb4 = (const f4_t*)hebb +
        (size_t)(b * H + hseg * 64 + half * 32) * (H / 4);
    f4_t acc = {0.f, 0.f, 0.f, 0.f};
    #pragma unroll 8
    for (int h = 0; h < 32; ++h) {
      f4_t v = hb4[(size_t)h * 128 + col];
      float s = h0s[half * 32 + h];
      acc += s * v;
    }
    if (half == 1) redv[col] = acc;
    __syncthreads();
    if (half == 0) {
      acc += redv[col];
      ((f4_t*)hbpart)[(size_t)(b * 8 + hseg) * 128 + col] = acc;
    }
    return;
  }

  // ---- GEMM path
  const int z   = bid >> 5;
  const int rem = bid & 31;
  const int n0  = (rem & 7) * BT;
  const int m0  = (rem >> 3) * BT;
  const int tx = t & 15, ty = t >> 4;

  float acc[4][4] = {{0.0f}};

  const float* Aseg[2]; const float* Bseg[2];
  int ldaS[2], KS[2]; int nseg; bool kmajor = true;
  const float* xb = nullptr; const float* hbias = nullptr;

  if (z < 3) {
    const float* xw; const float* hw_;
    if (z == 0)      { xw = x2f_w; xb = x2f_b; hw_ = h2f_w; hbias = h2f_b; }
    else if (z == 1) { xw = x2i_w; xb = x2i_b; hw_ = h2i_w; hbias = h2i_b; }
    else             { xw = x2o_w; xb = x2o_b; hw_ = h2o_w; hbias = h2o_b; }
    Aseg[0] = x;  ldaS[0] = ISZ; Bseg[0] = xw;  KS[0] = ISZ;
    Aseg[1] = h0; ldaS[1] = H;   Bseg[1] = hw_; KS[1] = H;
    nseg = 2;
  } else if (z == 3) {
    Aseg[0] = x; ldaS[0] = ISZ; Bseg[0] = x2c_w; KS[0] = ISZ; xb = x2c_b;
    nseg = 1;
  } else {
    Aseg[0] = h0; ldaS[0] = H; Bseg[0] = w; KS[0] = H;
    nseg = 1; kmajor = false;
  }

  for (int s = 0; s < nseg; ++s) {
    const float* A  = Aseg[s];
    const float* Bm = Bseg[s];
    const int lda = ldaS[s];
    const int K   = KS[s];
    for (int kk0 = 0; kk0 < K; kk0 += KT) {
      #pragma unroll
      for (int i = 0; i < 8; ++i) {
        int l = i * 256 + t;
        int j = l & 31, r = l >> 5;
        As[j][r] = A[(size_t)(m0 + r) * lda + kk0 + j];
      }
      if (kmajor) {
        #pragma unroll
        for (int i = 0; i < 8; ++i) {
          int l = i * 256 + t;
          int j = l & 31, n = l >> 5;
          Bs[j][n] = Bm[(size_t)(n0 + n) * K + kk0 + j];
        }
      } else {
        #pragma unroll
        for (int i = 0; i < 8; ++i) {
          int l = i * 256 + t;
          int n = l & 63, j = l >> 6;
          Bs[j][n] = Bm[(size_t)(kk0 + j) * H + n0 + n];
        }
      }
      __syncthreads();
      #pragma unroll
      for (int j = 0; j < KT; ++j) {
        float4 a  = *(const float4*)&As[j][ty * 4];
        float4 bv = *(const float4*)&Bs[j][tx * 4];
        float av[4] = {a.x, a.y, a.z, a.w};
        float bw[4] = {bv.x, bv.y, bv.z, bv.w};
        #pragma unroll
        for (int r = 0; r < 4; ++r)
          #pragma unroll
          for (int c = 0; c < 4; ++c)
            acc[r][c] += av[r] * bw[c];
      }
      __syncthreads();
    }
  }

  float bias[4];
  #pragma unroll
  for (int c = 0; c < 4; ++c) {
    int n = n0 + tx * 4 + c;
    float bv = 0.0f;
    if (z < 3)       bv = xb[n] + hbias[n];
    else if (z == 3) bv = xb[n];
    bias[c] = bv;
  }
  float* outc = pre + (size_t)z * BH;
  #pragma unroll
  for (int r = 0; r < 4; ++r) {
    int m = m0 + ty * 4 + r;
    float4 o;
    o.x = acc[r][0] + bias[0];
    o.y = acc[r][1] + bias[1];
    o.z = acc[r][2] + bias[2];
    o.w = acc[r][3] + bias[3];
    *(float4*)&outc[(size_t)m * H + n0 + tx * 4] = o;
  }
}

// ---------------- K-B: fused gates / cell / hactiv + modulator + eta ----------------
// one block per batch b; itc & hactiv never leave registers
__global__ __launch_bounds__(256) void fuse_mod(
    const float* __restrict__ pre, const float* __restrict__ hbpart,
    const float* __restrict__ c0, const float* __restrict__ alpha,
    const float* __restrict__ h2mod_w, const float* __restrict__ h2mod_b,
    const float* __restrict__ mfo_w, const float* __restrict__ mfo_b,
    float* __restrict__ out, float* __restrict__ eta)
{
  const int b = blockIdx.x, t = threadIdx.x;
  float ha[2], itcv[2];
  #pragma unroll
  for (int u = 0; u < 2; ++u) {
    const int k   = t + u * 256;
    const int idx = b * H + k;
    float hb = 0.0f;
    #pragma unroll
    for (int s = 0; s < 8; ++s) hb += hbpart[(size_t)(b * 8 + s) * H + k];
    float h2c = pre[(size_t)4 * BH + idx] + alpha[k] * hb;
    float it  = tanhf(pre[(size_t)3 * BH + idx] + h2c);
    float f = sigmoidf_(pre[idx]);
    float i = sigmoidf_(pre[(size_t)BH + idx]);
    float o = sigmoidf_(pre[(size_t)2 * BH + idx]);
    float cell = f * c0[idx] + i * it;
    float h = o * tanhf(cell);
    out[idx] = h;
    out[BH + idx] = cell;
    ha[u] = h; itcv[u] = it;
  }
  float s = ha[0] * h2mod_w[t] + ha[1] * h2mod_w[t + 256];
  #pragma unroll
  for (int off = 32; off > 0; off >>= 1) s += __shfl_down(s, off, 64);
  __shared__ float red[4];
  __shared__ float mm;
  if ((t & 63) == 0) red[t >> 6] = s;
  __syncthreads();
  if (t == 0) mm = tanhf(red[0] + red[1] + red[2] + red[3] + h2mod_b[0]);
  __syncthreads();
  float m = mm;
  #pragma unroll
  for (int u = 0; u < 2; ++u) {
    const int k = t + u * 256;
    eta[b * H + k] = (m * mfo_w[k] + mfo_b[k]) * itcv[u];
  }
}

// ---------------- K-C: hebb_new = clip(hebb + h0[b,h]*eta[b,k]) ----------------
// reversed block order: reads the L3-resident tail of hebb (left by K-A) first;
// nontemporal load/store so this kernel's own streams don't evict those lines.
__global__ __launch_bounds__(256) void hebb_update(
    const float* __restrict__ hebb, const float* __restrict__ h0,
    const float* __restrict__ eta, float* __restrict__ out)
{
  const size_t g = (size_t)(gridDim.x - 1 - blockIdx.x) * 256 + threadIdx.x;  // float4 idx
  f4_t v = nt_load4((const f4_t*)hebb + g);
  const int k4  = (int)(g & 127);
  const int row = (int)(g >> 7);           // b*512 + h
  const int b   = row >> 9;
  f4_t e = ((const f4_t*)eta)[(b << 7) + k4];
  float s = h0[row];
  f4_t r;
  r.x = fminf(fmaxf(v.x + s * e.x, -CLIPV), CLIPV);
  r.y = fminf(fmaxf(v.y + s * e.y, -CLIPV), CLIPV);
  r.z = fminf(fmaxf(v.z + s * e.z, -CLIPV), CLIPV);
  r.w = fminf(fmaxf(v.w + s * e.w, -CLIPV), CLIPV);
  nt_store4((f4_t*)out + (size_t)(2 * BH / 4) + g, r);
}

extern "C" void kernel_launch(void* const* d_in, const int* in_sizes, int n_in,
                              void* d_out, int out_size, void* d_ws, size_t ws_size,
                              hipStream_t stream) {
  const float* x       = (const float*)d_in[0];
  const float* h0      = (const float*)d_in[1];
  const float* c0      = (const float*)d_in[2];
  const float* hebb    = (const float*)d_in[3];
  const float* w       = (const float*)d_in[4];
  const float* alpha   = (const float*)d_in[5];
  const float* h2f_w   = (const float*)d_in[6];
  const float* h2f_b   = (const float*)d_in[7];
  const float* h2i_w   = (const float*)d_in[8];
  const float* h2i_b   = (const float*)d_in[9];
  const float* h2o_w   = (const float*)d_in[10];
  const float* h2o_b   = (const float*)d_in[11];
  const float* x2f_w   = (const float*)d_in[12];
  const float* x2f_b   = (const float*)d_in[13];
  const float* x2i_w   = (const float*)d_in[14];
  const float* x2i_b   = (const float*)d_in[15];
  const float* x2o_w   = (const float*)d_in[16];
  const float* x2o_b   = (const float*)d_in[17];
  const float* x2c_w   = (const float*)d_in[18];
  const float* x2c_b   = (const float*)d_in[19];
  const float* h2mod_w = (const float*)d_in[20];
  const float* h2mod_b = (const float*)d_in[21];
  const float* mfo_w   = (const float*)d_in[22];
  const float* mfo_b   = (const float*)d_in[23];

  float* out = (float*)d_out;
  float* ws  = (float*)d_ws;

  float* pre    = ws;                          // 5 * 131072
  float* hbpart = pre + (size_t)5 * BH;        // 256*8*512 = 1048576
  float* eta    = hbpart + (size_t)BATCH * 8 * H;   // 131072; total ~7.3 MB

  gemms_einsum<<<NGEMM + NEIN, 256, 0, stream>>>(
      x, h0, x2f_w, x2f_b, h2f_w, h2f_b, x2i_w, x2i_b, h2i_w, h2i_b,
      x2o_w, x2o_b, h2o_w, h2o_b, x2c_w, x2c_b, w, hebb, pre, hbpart);

  fuse_mod<<<BATCH, 256, 0, stream>>>(
      pre, hbpart, c0, alpha, h2mod_w, h2mod_b, mfo_w, mfo_b, out, eta);

  hebb_update<<<(BH * (H / 4)) / 256, 256, 0, stream>>>(hebb, h0, eta, out);
}

// Round 2
// 541.065 us; speedup vs baseline: 1.2446x; 1.1624x over previous
//
#include <hip/hip_runtime.h>
#include <math.h>

#define BATCH 256
#define ISZ 256
#define H 512
#define BH (BATCH * H)       // 131072
#define CLIPV 2.0f

typedef float f4_t __attribute__((ext_vector_type(4)));

__device__ __forceinline__ float sigmoidf_(float x) { return 1.0f / (1.0f + expf(-x)); }
__device__ __forceinline__ f4_t nt_load4(const f4_t* p) { return __builtin_nontemporal_load(p); }
__device__ __forceinline__ void nt_store4(f4_t* p, f4_t v) { __builtin_nontemporal_store(v, p); }

// ---------------- K-A: merged chunked GEMMs + einsum partials ----------------
// blocks [0, 256):    8 chunk-GEMMs x 32 tiles (64x64), all outputs [256 x 512]:
//   ch0: x@x2f_w^T (+both f biases)   K=256 | ch1: h0@h2f_w^T  K=512
//   ch2: x@x2i_w^T (+both i biases)   K=256 | ch3: h0@h2i_w^T  K=512
//   ch4: x@x2o_w^T (+both o biases)   K=256 | ch5: h0@h2o_w^T  K=512
//   ch6: x@x2c_w^T (+x2c_b)           K=256 | ch7: h0@w (n-major) K=512
//   fuse_mod sums the chunk pairs. 256 blocks ~ 1/CU -> no serial tail.
// blocks [256, 1280): einsum partial hbpart[b,seg,k] = sum_{h in 128-seg} h0*hebb
#define BT 64
#define KT 32
#define LDSP (BT + 4)
#define NGEMM 256
#define NEIN  1024

__global__ __launch_bounds__(256) void gemms_einsum(
    const float* __restrict__ x, const float* __restrict__ h0,
    const float* __restrict__ x2f_w, const float* __restrict__ x2f_b,
    const float* __restrict__ h2f_w, const float* __restrict__ h2f_b,
    const float* __restrict__ x2i_w, const float* __restrict__ x2i_b,
    const float* __restrict__ h2i_w, const float* __restrict__ h2i_b,
    const float* __restrict__ x2o_w, const float* __restrict__ x2o_b,
    const float* __restrict__ h2o_w, const float* __restrict__ h2o_b,
    const float* __restrict__ x2c_w, const float* __restrict__ x2c_b,
    const float* __restrict__ w,
    const float* __restrict__ hebb,
    float* __restrict__ pre, float* __restrict__ hbpart)
{
  __shared__ __align__(16) float As[KT][LDSP];
  __shared__ __align__(16) float Bs[KT][LDSP];
  __shared__ float h0s[128];
  __shared__ f4_t redv[128];

  const int bid = blockIdx.x;
  const int t   = threadIdx.x;

  if (bid >= NGEMM) {
    // ---- einsum path: (b, seg of 128 h-rows); 256 thr = 2 halves x 128 f4-cols
    const int e    = bid - NGEMM;
    const int b    = e >> 2;
    const int seg  = e & 3;
    const int col  = t & 127;
    const int half = t >> 7;
    if (t < 128) h0s[t] = h0[b * H + seg * 128 + t];
    __syncthreads();
    const f4_t* hb4 = (const f4_t*)hebb +
        (size_t)(b * H + seg * 128 + half * 64) * (H / 4) + col;
    f4_t acc = {0.f, 0.f, 0.f, 0.f};
    #pragma unroll 8
    for (int h = 0; h < 64; ++h) {
      acc += h0s[half * 64 + h] * hb4[(size_t)h * 128];
    }
    if (half == 1) redv[col] = acc;
    __syncthreads();
    if (half == 0) {
      acc += redv[col];
      ((f4_t*)hbpart)[(size_t)(b * 4 + seg) * 128 + col] = acc;
    }
    return;
  }

  // ---- GEMM path: one 64x64 tile of one chunk
  const int ch  = bid >> 5;
  const int rem = bid & 31;
  const int n0  = (rem & 7) * BT;
  const int m0  = (rem >> 3) * BT;
  const int tx = t & 15, ty = t >> 4;

  const float* A; const float* Bm; int lda, K; bool kmajor = true;
  const float* b1 = nullptr; const float* b2 = nullptr;
  switch (ch) {
    case 0: A = x;  lda = ISZ; K = ISZ; Bm = x2f_w; b1 = x2f_b; b2 = h2f_b; break;
    case 1: A = h0; lda = H;   K = H;   Bm = h2f_w; break;
    case 2: A = x;  lda = ISZ; K = ISZ; Bm = x2i_w; b1 = x2i_b; b2 = h2i_b; break;
    case 3: A = h0; lda = H;   K = H;   Bm = h2i_w; break;
    case 4: A = x;  lda = ISZ; K = ISZ; Bm = x2o_w; b1 = x2o_b; b2 = h2o_b; break;
    case 5: A = h0; lda = H;   K = H;   Bm = h2o_w; break;
    case 6: A = x;  lda = ISZ; K = ISZ; Bm = x2c_w; b1 = x2c_b; break;
    default: A = h0; lda = H;  K = H;   Bm = w; kmajor = false; break;
  }

  float acc[4][4] = {{0.0f}};

  for (int kk0 = 0; kk0 < K; kk0 += KT) {
    // stage A tile [KT x BT]: float4 global loads, transposed LDS scatter
    #pragma unroll
    for (int i = 0; i < 2; ++i) {
      int l = i * 256 + t;          // 0..511 f4 elems (64 rows x 8 f4)
      int r = l >> 3, c = l & 7;
      float4 v = *(const float4*)&A[(size_t)(m0 + r) * lda + kk0 + c * 4];
      As[c * 4 + 0][r] = v.x; As[c * 4 + 1][r] = v.y;
      As[c * 4 + 2][r] = v.z; As[c * 4 + 3][r] = v.w;
    }
    if (kmajor) {
      #pragma unroll
      for (int i = 0; i < 2; ++i) {
        int l = i * 256 + t;
        int n = l >> 3, c = l & 7;
        float4 v = *(const float4*)&Bm[(size_t)(n0 + n) * K + kk0 + c * 4];
        Bs[c * 4 + 0][n] = v.x; Bs[c * 4 + 1][n] = v.y;
        Bs[c * 4 + 2][n] = v.z; Bs[c * 4 + 3][n] = v.w;
      }
    } else {
      #pragma unroll
      for (int i = 0; i < 2; ++i) {
        int l = i * 256 + t;          // 32 j x 16 f4
        int j = l >> 4, c = l & 15;
        float4 v = *(const float4*)&Bm[(size_t)(kk0 + j) * H + n0 + c * 4];
        *(float4*)&Bs[j][c * 4] = v;
      }
    }
    __syncthreads();
    #pragma unroll
    for (int j = 0; j < KT; ++j) {
      float4 a  = *(const float4*)&As[j][ty * 4];
      float4 bv = *(const float4*)&Bs[j][tx * 4];
      float av[4] = {a.x, a.y, a.z, a.w};
      float bw[4] = {bv.x, bv.y, bv.z, bv.w};
      #pragma unroll
      for (int r = 0; r < 4; ++r)
        #pragma unroll
        for (int c = 0; c < 4; ++c)
          acc[r][c] += av[r] * bw[c];
    }
    __syncthreads();
  }

  float bias[4];
  #pragma unroll
  for (int c = 0; c < 4; ++c) {
    int n = n0 + tx * 4 + c;
    float bv = 0.0f;
    if (b1) bv += b1[n];
    if (b2) bv += b2[n];
    bias[c] = bv;
  }
  float* outc = pre + (size_t)ch * BH;
  #pragma unroll
  for (int r = 0; r < 4; ++r) {
    int m = m0 + ty * 4 + r;
    float4 o;
    o.x = acc[r][0] + bias[0];
    o.y = acc[r][1] + bias[1];
    o.z = acc[r][2] + bias[2];
    o.w = acc[r][3] + bias[3];
    *(float4*)&outc[(size_t)m * H + n0 + tx * 4] = o;
  }
}

// ---------------- K-B: fused gates / cell / hactiv + modulator + eta ----------------
__global__ __launch_bounds__(256) void fuse_mod(
    const float* __restrict__ pre, const float* __restrict__ hbpart,
    const float* __restrict__ c0, const float* __restrict__ alpha,
    const float* __restrict__ h2mod_w, const float* __restrict__ h2mod_b,
    const float* __restrict__ mfo_w, const float* __restrict__ mfo_b,
    float* __restrict__ out, float* __restrict__ eta)
{
  const int b = blockIdx.x, t = threadIdx.x;
  float ha[2], itcv[2];
  #pragma unroll
  for (int u = 0; u < 2; ++u) {
    const int k   = t + u * 256;
    const int idx = b * H + k;
    float hb = 0.0f;
    #pragma unroll
    for (int s = 0; s < 4; ++s) hb += hbpart[(size_t)(b * 4 + s) * H + k];
    float h2c = pre[(size_t)7 * BH + idx] + alpha[k] * hb;
    float it  = tanhf(pre[(size_t)6 * BH + idx] + h2c);
    float f = sigmoidf_(pre[idx]                + pre[(size_t)1 * BH + idx]);
    float i = sigmoidf_(pre[(size_t)2 * BH + idx] + pre[(size_t)3 * BH + idx]);
    float o = sigmoidf_(pre[(size_t)4 * BH + idx] + pre[(size_t)5 * BH + idx]);
    float cell = f * c0[idx] + i * it;
    float h = o * tanhf(cell);
    out[idx] = h;
    out[BH + idx] = cell;
    ha[u] = h; itcv[u] = it;
  }
  float s = ha[0] * h2mod_w[t] + ha[1] * h2mod_w[t + 256];
  #pragma unroll
  for (int off = 32; off > 0; off >>= 1) s += __shfl_down(s, off, 64);
  __shared__ float red[4];
  __shared__ float mm;
  if ((t & 63) == 0) red[t >> 6] = s;
  __syncthreads();
  if (t == 0) mm = tanhf(red[0] + red[1] + red[2] + red[3] + h2mod_b[0]);
  __syncthreads();
  float m = mm;
  #pragma unroll
  for (int u = 0; u < 2; ++u) {
    const int k = t + u * 256;
    eta[b * H + k] = (m * mfo_w[k] + mfo_b[k]) * itcv[u];
  }
}

// ---------------- K-C: hebb_new = clip(hebb + h0[b,h]*eta[b,k]) ----------------
// reversed block order reads the L3-resident tail of hebb (left by K-A) first;
// nontemporal load/store keeps those lines from being evicted by our own stream.
__global__ __launch_bounds__(256) void hebb_update(
    const float* __restrict__ hebb, const float* __restrict__ h0,
    const float* __restrict__ eta, float* __restrict__ out)
{
  const size_t g = (size_t)(gridDim.x - 1 - blockIdx.x) * 256 + threadIdx.x;  // f4 idx
  f4_t v = nt_load4((const f4_t*)hebb + g);
  const int k4  = (int)(g & 127);
  const int row = (int)(g >> 7);           // b*512 + h
  const int b   = row >> 9;
  f4_t e = ((const f4_t*)eta)[(b << 7) + k4];
  float s = h0[row];
  f4_t r;
  r.x = fminf(fmaxf(v.x + s * e.x, -CLIPV), CLIPV);
  r.y = fminf(fmaxf(v.y + s * e.y, -CLIPV), CLIPV);
  r.z = fminf(fmaxf(v.z + s * e.z, -CLIPV), CLIPV);
  r.w = fminf(fmaxf(v.w + s * e.w, -CLIPV), CLIPV);
  nt_store4((f4_t*)out + (size_t)(2 * BH / 4) + g, r);
}

extern "C" void kernel_launch(void* const* d_in, const int* in_sizes, int n_in,
                              void* d_out, int out_size, void* d_ws, size_t ws_size,
                              hipStream_t stream) {
  const float* x       = (const float*)d_in[0];
  const float* h0      = (const float*)d_in[1];
  const float* c0      = (const float*)d_in[2];
  const float* hebb    = (const float*)d_in[3];
  const float* w       = (const float*)d_in[4];
  const float* alpha   = (const float*)d_in[5];
  const float* h2f_w   = (const float*)d_in[6];
  const float* h2f_b   = (const float*)d_in[7];
  const float* h2i_w   = (const float*)d_in[8];
  const float* h2i_b   = (const float*)d_in[9];
  const float* h2o_w   = (const float*)d_in[10];
  const float* h2o_b   = (const float*)d_in[11];
  const float* x2f_w   = (const float*)d_in[12];
  const float* x2f_b   = (const float*)d_in[13];
  const float* x2i_w   = (const float*)d_in[14];
  const float* x2i_b   = (const float*)d_in[15];
  const float* x2o_w   = (const float*)d_in[16];
  const float* x2o_b   = (const float*)d_in[17];
  const float* x2c_w   = (const float*)d_in[18];
  const float* x2c_b   = (const float*)d_in[19];
  const float* h2mod_w = (const float*)d_in[20];
  const float* h2mod_b = (const float*)d_in[21];
  const float* mfo_w   = (const float*)d_in[22];
  const float* mfo_b   = (const float*)d_in[23];

  float* out = (float*)d_out;
  float* ws  = (float*)d_ws;

  float* pre    = ws;                               // 8 * 131072      (4.19 MB)
  float* hbpart = pre + (size_t)8 * BH;             // 256*4*512      (2.10 MB)
  float* eta    = hbpart + (size_t)BATCH * 4 * H;   // 131072         (0.52 MB)

  gemms_einsum<<<NGEMM + NEIN, 256, 0, stream>>>(
      x, h0, x2f_w, x2f_b, h2f_w, h2f_b, x2i_w, x2i_b, h2i_w, h2i_b,
      x2o_w, x2o_b, h2o_w, h2o_b, x2c_w, x2c_b, w, hebb, pre, hbpart);

  fuse_mod<<<BATCH, 256, 0, stream>>>(
      pre, hbpart, c0, alpha, h2mod_w, h2mod_b, mfo_w, mfo_b, out, eta);

  hebb_update<<<(BH * (H / 4)) / 256, 256, 0, stream>>>(hebb, h0, eta, out);
}